// Round 16
// baseline (371.067 us; speedup 1.0000x reference)
//
#include <hip/hip_runtime.h>
#include <math.h>

#define NN 100000
#define EE 1600000
#define FIN 256
#define D1 64
#define D2 160
#define C2 40
#define P1R 72    // padded l1 row: 64 ch + 8 omega (f16) = 144 B
#define P2R 168   // padded l2 row: 160 ch + 4 omega + 4 pad (f16) = 336 B
#define PK1 264   // gemm1 W LDS k-pitch
#define PK2 72    // gemm2 W LDS k-pitch
#define NBUCK 391 // ceil(NN/256) dst buckets
#define CAP 5000  // max edges per dst bucket incl. self loops
#define NSB 25    // coarse src buckets (src>>12)
#define CAPS 68000// max edges per src bucket (mean 64000, ~16 sigma)
#define BPB 34    // part1 blocks per src bucket (34*2048 >= CAPS)
#define WSCL 0.015625f
#define L2E 1.442695041f
#define RB1 (P1R*2)   // 144 B l1 row
#define RB2 (P2R*2)   // 336 B l2 row

typedef unsigned short u16;
typedef __attribute__((ext_vector_type(8))) short bf16x8;
typedef __attribute__((ext_vector_type(4))) float f32x4;
typedef _Float16 h2t __attribute__((ext_vector_type(2)));
union hu { unsigned u; h2t h; };

__device__ __forceinline__ u16 f2bf(float f){
  unsigned b = __float_as_uint(f);
  return (u16)((b + 0x7FFFu + ((b >> 16) & 1u)) >> 16);   // RNE
}
__device__ __forceinline__ u16 f2h(float f){
  union { _Float16 h; u16 u; } c; c.h = (_Float16)f; return c.u;
}
__device__ __forceinline__ float h16f(u16 v){
  union { u16 u; _Float16 h; } c; c.u = v; return (float)c.h;
}

// ---------------- weight-side att precompute (parallel) ----------------
__global__ void wprep_k(const float* __restrict__ Wl1, const float* __restrict__ Wr1,
                        const float* __restrict__ att1,
                        const float* __restrict__ bl1, const float* __restrict__ br1,
                        const float* __restrict__ Wl2, const float* __restrict__ Wr2,
                        const float* __restrict__ att2,
                        const float* __restrict__ bl2, const float* __restrict__ br2,
                        float* __restrict__ WA1, float* __restrict__ BA1,
                        float* __restrict__ WA2, float* __restrict__ BA2){
  int t = blockIdx.x*256 + threadIdx.x;
  if (t < 4096){
    int k = t >> 4, j = t & 15;
    float v = 0.f;
    if (j < 8){
      float s = 0.f;
      #pragma unroll
      for (int c = 0; c < 8; ++c) s += Wl1[(size_t)k*D1 + j*8 + c] * att1[j*8 + c];
      v = 0.6f * s;
    }
    WA1[t] = v;
  } else if (t < 4608){
    int i = t - 4096;
    int k = i >> 3, j = i & 7;
    float v = 0.f;
    if (j < 4){
      float s = 0.f;
      #pragma unroll
      for (int c = 0; c < 40; ++c) s += Wl2[(size_t)k*D2 + j*40 + c] * att2[j*40 + c];
      v = 0.6f * s;
    }
    WA2[i] = v;
  } else if (t < 4616){
    int j = t - 4608;
    float s = 0.f;
    #pragma unroll
    for (int c = 0; c < 8; ++c) s += bl1[j*8 + c] * att1[j*8 + c];
    BA1[j] = 0.6f * s;
  } else if (t < 4620){
    int j = t - 4616;
    float s = 0.f;
    #pragma unroll
    for (int c = 0; c < 40; ++c) s += bl2[j*40 + c] * att2[j*40 + c];
    BA2[j] = 0.6f * s;
  }
}

// ---- phase A: coarse-bucket edges by src>>12 (locality pre-sort) ----
__global__ __launch_bounds__(256) void psortA_k(const int* __restrict__ ei,
                                                int* __restrict__ pcnt,
                                                int2* __restrict__ ptmp){
  __shared__ int hist[NSB];
  __shared__ int gbase[NSB];
  int t = threadIdx.x;
  if (t < NSB) hist[t] = 0;
  __syncthreads();
  int rb[8], rr[8]; int2 rv[8];
  #pragma unroll
  for (int q = 0; q < 8; ++q){
    int e = blockIdx.x*2048 + q*256 + t;
    rb[q] = -1;
    if (e < EE){
      int s = ei[e], d = ei[EE + e];
      int b = s >> 12;
      rb[q] = b;
      rv[q] = make_int2(s, d);
      rr[q] = atomicAdd(&hist[b], 1);
    }
  }
  __syncthreads();
  if (t < NSB && hist[t] > 0) gbase[t] = atomicAdd(&pcnt[t], hist[t]);
  __syncthreads();
  #pragma unroll
  for (int q = 0; q < 8; ++q){
    if (rb[q] >= 0){
      int pos = gbase[rb[q]] + rr[q];
      if (pos < CAPS) ptmp[(size_t)rb[q]*CAPS + pos] = rv[q];
    }
  }
}

// ---- phase B: dst-bucket partition, consuming edges in coarse-src order ----
__global__ __launch_bounds__(256) void part1_k(const int2* __restrict__ ptmp,
                                               const int* __restrict__ pcnt,
                                               int* __restrict__ bcnt,
                                               int* __restrict__ csrtmp){
  __shared__ int hist[NBUCK];
  __shared__ int gbase[NBUCK];
  int t = threadIdx.x;
  int sb = blockIdx.x / BPB, sl = blockIdx.x % BPB;
  int cnt = pcnt[sb]; if (cnt > CAPS) cnt = CAPS;
  for (int i = t; i < NBUCK; i += 256) hist[i] = 0;
  __syncthreads();
  int rb[8], rr[8], rv[8];
  #pragma unroll
  for (int q = 0; q < 8; ++q){
    int i = sl*2048 + q*256 + t;
    rb[q] = -1;
    if (i < cnt){
      int2 sd = ptmp[(size_t)sb*CAPS + i];
      int b = sd.y >> 8;
      rb[q] = b;
      rv[q] = sd.x | ((sd.y & 255) << 17);
      rr[q] = atomicAdd(&hist[b], 1);
    }
  }
  __syncthreads();
  for (int i = t; i < NBUCK; i += 256)
    if (hist[i] > 0) gbase[i] = atomicAdd(&bcnt[i], hist[i]);
  __syncthreads();
  #pragma unroll
  for (int q = 0; q < 8; ++q){
    if (rb[q] >= 0){
      int pos = gbase[rb[q]] + rr[q];
      if (pos < CAP) csrtmp[rb[q]*CAP + pos] = rv[q];
    }
  }
}

// pass 2: per-bucket LDS counting sort; self loop seeded first.
// csr1/csr2 hold PRE-MULTIPLIED ROW BYTE OFFSETS (src*RB1, src*RB2).
__global__ __launch_bounds__(256) void sort_k(const int* __restrict__ bcnt,
                                              const int* __restrict__ csrtmp,
                                              int* __restrict__ csr1,
                                              int* __restrict__ csr2,
                                              int* __restrict__ off,
                                              int* __restrict__ end){
  __shared__ int cnt[256];
  __shared__ int sc[256];
  __shared__ int cur[256];
  int b = blockIdx.x, t = threadIdx.x;
  int E = bcnt[b]; if (E > CAP) E = CAP;
  int n = (b << 8) + t;
  cnt[t] = (n < NN) ? 1 : 0;          // self edge
  __syncthreads();
  for (int i = t; i < E; i += 256){
    int v = csrtmp[b*CAP + i];
    atomicAdd(&cnt[(v >> 17) & 255], 1);
  }
  __syncthreads();
  int x = cnt[t];
  sc[t] = x;
  __syncthreads();
  for (int o = 1; o < 256; o <<= 1){
    int v = (t >= o) ? sc[t - o] : 0;
    __syncthreads();
    sc[t] += v;
    __syncthreads();
  }
  int excl = sc[t] - x;
  if (n < NN){
    off[n] = b*CAP + excl;
    end[n] = b*CAP + excl + x;
    csr1[b*CAP + excl] = n * RB1;     // self edge first
    csr2[b*CAP + excl] = n * RB2;
    cur[t] = excl + 1;
  } else {
    cur[t] = excl;
  }
  __syncthreads();
  // preserve arrival (coarse-src) order: process in index order per thread's
  // dst via the same strided loop (stable enough at 1.6MB granularity)
  for (int i = t; i < E; i += 256){
    int v = csrtmp[b*CAP + i];
    int p = atomicAdd(&cur[(v >> 17) & 255], 1);
    int src = v & 0x1FFFF;
    csr1[b*CAP + p] = src * RB1;
    csr2[b*CAP + p] = src * RB2;
  }
}

// ---------------- layer-1 MFMA GEMM + omega channel (f16 out) ----------------
__global__ __launch_bounds__(256) void gemm1_mfma(
    const float* __restrict__ X,
    const float* __restrict__ Wl, const float* __restrict__ bl,
    const float* __restrict__ Wr, const float* __restrict__ br,
    const float* __restrict__ WA1, const float* __restrict__ BA1,
    u16* __restrict__ outl, u16* __restrict__ outr){
  __shared__ u16 WB[144*PK1];   // 76 KB
  int t = threadIdx.x;
  #pragma unroll
  for (int q = 0; q < 16; ++q){
    int idx = t + 256*q;
    int k = idx >> 4, c4 = idx & 15;
    float4 vl = *reinterpret_cast<const float4*>(Wl + (size_t)k*D1 + c4*4);
    float4 vr = *reinterpret_cast<const float4*>(Wr + (size_t)k*D1 + c4*4);
    WB[(c4*4+0)*PK1 + k] = f2bf(vl.x); WB[(c4*4+1)*PK1 + k] = f2bf(vl.y);
    WB[(c4*4+2)*PK1 + k] = f2bf(vl.z); WB[(c4*4+3)*PK1 + k] = f2bf(vl.w);
    WB[(64+c4*4+0)*PK1 + k] = f2bf(vr.x); WB[(64+c4*4+1)*PK1 + k] = f2bf(vr.y);
    WB[(64+c4*4+2)*PK1 + k] = f2bf(vr.z); WB[(64+c4*4+3)*PK1 + k] = f2bf(vr.w);
  }
  #pragma unroll
  for (int q = 0; q < 16; ++q){
    int idx = t + 256*q;
    int k = idx >> 4, j = idx & 15;
    WB[(128+j)*PK1 + k] = f2bf(WA1[k*16 + j]);
  }
  __syncthreads();
  int w = t >> 6, l = t & 63;
  int g = l >> 4;
  int arow = blockIdx.x*64 + w*16 + (l & 15);
  if (arow >= NN) arow = NN-1;
  const float* xp = X + (size_t)arow*FIN + g*8;
  f32x4 acc[9] = {};
  #pragma unroll
  for (int kk = 0; kk < 8; ++kk){
    float4 a0 = *reinterpret_cast<const float4*>(xp + kk*32);
    float4 a1 = *reinterpret_cast<const float4*>(xp + kk*32 + 4);
    union { bf16x8 v; u16 u[8]; } A;
    A.u[0]=f2bf(a0.x); A.u[1]=f2bf(a0.y); A.u[2]=f2bf(a0.z); A.u[3]=f2bf(a0.w);
    A.u[4]=f2bf(a1.x); A.u[5]=f2bf(a1.y); A.u[6]=f2bf(a1.z); A.u[7]=f2bf(a1.w);
    const u16* wb = WB + (l & 15)*PK1 + kk*32 + g*8;
    #pragma unroll
    for (int c = 0; c < 9; ++c){
      bf16x8 B = *reinterpret_cast<const bf16x8*>(wb + c*16*PK1);
      acc[c] = __builtin_amdgcn_mfma_f32_16x16x32_bf16(A.v, B, acc[c], 0, 0, 0);
    }
  }
  int ocol = l & 15;
  int orow0 = blockIdx.x*64 + w*16 + g*4;
  #pragma unroll
  for (int c = 0; c < 8; ++c){
    bool left = (c < 4);
    int col = (left ? c : c-4)*16 + ocol;
    u16* op = left ? outl : outr;
    float bv = (left ? bl : br)[col];
    #pragma unroll
    for (int r = 0; r < 4; ++r){
      int row = orow0 + r;
      if (row < NN) op[(size_t)row*P1R + col] = f2h(acc[c][r] + bv);
    }
  }
  if (ocol < 8){
    float bav = BA1[ocol];
    #pragma unroll
    for (int r = 0; r < 4; ++r){
      int row = orow0 + r;
      if (row < NN) outl[(size_t)row*P1R + 64 + ocol] = f2h(__expf(acc[8][r] + bav) * WSCL);
    }
  }
}

// ---------------- layer-2 dual MFMA GEMM + omega channel (f16 out) ------------
__global__ __launch_bounds__(256) void gemm2_mfma(
    const u16* __restrict__ H,
    const float* __restrict__ Wl, const float* __restrict__ bl,
    const float* __restrict__ Wr, const float* __restrict__ br,
    const float* __restrict__ WA2, const float* __restrict__ BA2,
    u16* __restrict__ outl, u16* __restrict__ outr){
  __shared__ u16 WB[336*PK2];   // 48.4 KB
  int t = threadIdx.x;
  #pragma unroll
  for (int q = 0; q < 10; ++q){
    int idx = t + 256*q;
    int k = idx / 40, c4 = idx % 40;
    float4 vl = *reinterpret_cast<const float4*>(Wl + (size_t)k*D2 + c4*4);
    float4 vr = *reinterpret_cast<const float4*>(Wr + (size_t)k*D2 + c4*4);
    WB[(c4*4+0)*PK2 + k] = f2bf(vl.x); WB[(c4*4+1)*PK2 + k] = f2bf(vl.y);
    WB[(c4*4+2)*PK2 + k] = f2bf(vl.z); WB[(c4*4+3)*PK2 + k] = f2bf(vl.w);
    WB[(160+c4*4+0)*PK2 + k] = f2bf(vr.x); WB[(160+c4*4+1)*PK2 + k] = f2bf(vr.y);
    WB[(160+c4*4+2)*PK2 + k] = f2bf(vr.z); WB[(160+c4*4+3)*PK2 + k] = f2bf(vr.w);
  }
  #pragma unroll
  for (int q = 0; q < 2; ++q){
    int i2 = t + 256*q;
    int k = i2 >> 3, j = i2 & 7;
    WB[(320+j)*PK2 + k] = f2bf(WA2[k*8 + j]);
    WB[(328+j)*PK2 + k] = 0;
  }
  __syncthreads();
  int w = t >> 6, l = t & 63;
  int g = l >> 4;
  int arow = blockIdx.x*64 + w*16 + (l & 15);
  if (arow >= NN) arow = NN-1;
  const u16* hp = H + (size_t)arow*D1 + g*8;
  f32x4 acc[21] = {};
  #pragma unroll
  for (int kk = 0; kk < 2; ++kk){
    bf16x8 A = *reinterpret_cast<const bf16x8*>(hp + kk*32);
    const u16* wb = WB + (l & 15)*PK2 + kk*32 + g*8;
    #pragma unroll
    for (int c = 0; c < 21; ++c){
      bf16x8 B = *reinterpret_cast<const bf16x8*>(wb + c*16*PK2);
      acc[c] = __builtin_amdgcn_mfma_f32_16x16x32_bf16(A, B, acc[c], 0, 0, 0);
    }
  }
  int ocol = l & 15;
  int orow0 = blockIdx.x*64 + w*16 + g*4;
  #pragma unroll
  for (int c = 0; c < 20; ++c){
    bool left = (c < 10);
    int col = (left ? c : c-10)*16 + ocol;
    u16* op = left ? outl : outr;
    float bv = (left ? bl : br)[col];
    #pragma unroll
    for (int r = 0; r < 4; ++r){
      int row = orow0 + r;
      if (row < NN) op[(size_t)row*P2R + col] = f2h(acc[c][r] + bv);
    }
  }
  if (ocol < 4){
    float bav = BA2[ocol];
    #pragma unroll
    for (int r = 0; r < 4; ++r){
      int row = orow0 + r;
      if (row < NN) outl[(size_t)row*P2R + 160 + ocol] = f2h(__expf(acc[20][r] + bav) * WSCL);
    }
  }
}

// ---------------- Layer 1 fused: byte-offset csr, packed-f16, 4-edge unroll --
__global__ void l1_fused(const u16* __restrict__ xl, const u16* __restrict__ xr,
                         const int* __restrict__ off, const int* __restrict__ end,
                         const int* __restrict__ csr1,
                         const float* __restrict__ att,
                         const float* __restrict__ b, u16* __restrict__ out){
  int tid = threadIdx.x;
  int lane = tid & 63;
  int g = (lane >> 4) & 1, l = lane & 15;
  int n = blockIdx.x*8 + (tid >> 6)*2 + (lane >> 5);
  if (n >= NN) return;
  int h = l >> 1;
  const char* xlb = (const char*)xl;
  int lo = 8*l;
  int wo = 128 + 2*h;
  uint2 xru = *reinterpret_cast<const uint2*>(xr + (size_t)n*P1R + 4*l);
  hu r0, r1; r0.u = xru.x; r1.u = xru.y;
  hu a0, a1;
  a0.h[0] = (_Float16)(0.4f*L2E*att[4*l+0]); a0.h[1] = (_Float16)(0.4f*L2E*att[4*l+1]);
  a1.h[0] = (_Float16)(0.4f*L2E*att[4*l+2]); a1.h[1] = (_Float16)(0.4f*L2E*att[4*l+3]);
  float s = 0.f;
  hu acc0, acc1; acc0.u = 0; acc1.u = 0;
  int p = off[n] + g, e1 = end[n];
  for (; p + 6 < e1; p += 8){
    unsigned bo[4];
    #pragma unroll
    for (int q = 0; q < 4; ++q) bo[q] = (unsigned)csr1[p + 2*q];
    uint2 uv[4]; u16 wv[4];
    #pragma unroll
    for (int q = 0; q < 4; ++q){
      uv[q] = *reinterpret_cast<const uint2*>(xlb + bo[q] + lo);
      wv[q] = *reinterpret_cast<const u16*>(xlb + bo[q] + wo);
    }
    #pragma unroll
    for (int q = 0; q < 4; ++q){
      hu x0, x1; x0.u = uv[q].x; x1.u = uv[q].y;
      hu y0, y1; y0.h = x0.h + r0.h; y1.h = x1.h + r1.h;
      y0.u &= 0x7FFF7FFFu; y1.u &= 0x7FFF7FFFu;
      hu t2; t2.h = a0.h*y0.h + a1.h*y1.h;
      float tf = (float)t2.h[0] + (float)t2.h[1];
      tf += __shfl_xor(tf, 1);
      float pa = __builtin_amdgcn_exp2f(tf) * h16f(wv[q]);
      s += pa;
      hu pp; pp.h[0] = (_Float16)pa; pp.h[1] = pp.h[0];
      acc0.h = pp.h*x0.h + acc0.h;
      acc1.h = pp.h*x1.h + acc1.h;
    }
  }
  for (; p < e1; p += 2){
    unsigned bo = (unsigned)csr1[p];
    uint2 ua = *reinterpret_cast<const uint2*>(xlb + bo + lo);
    u16 wa = *reinterpret_cast<const u16*>(xlb + bo + wo);
    hu x0, x1; x0.u = ua.x; x1.u = ua.y;
    hu y0, y1; y0.h = x0.h + r0.h; y1.h = x1.h + r1.h;
    y0.u &= 0x7FFF7FFFu; y1.u &= 0x7FFF7FFFu;
    hu t2; t2.h = a0.h*y0.h + a1.h*y1.h;
    float tf = (float)t2.h[0] + (float)t2.h[1];
    tf += __shfl_xor(tf, 1);
    float pa = __builtin_amdgcn_exp2f(tf) * h16f(wa);
    s += pa;
    hu pp; pp.h[0] = (_Float16)pa; pp.h[1] = pp.h[0];
    acc0.h = pp.h*x0.h + acc0.h;
    acc1.h = pp.h*x1.h + acc1.h;
  }
  s += __shfl_xor(s, 16);
  { hu m; m.u = (unsigned)__shfl_xor((int)acc0.u, 16); acc0.h = acc0.h + m.h; }
  { hu m; m.u = (unsigned)__shfl_xor((int)acc1.u, 16); acc1.h = acc1.h + m.h; }
  if (g == 0){
    float inv = 1.f / (s + 1e-16f);
    float v0 = (float)acc0.h[0]*inv + b[4*l+0];
    float v1 = (float)acc0.h[1]*inv + b[4*l+1];
    float v2 = (float)acc1.h[0]*inv + b[4*l+2];
    float v3 = (float)acc1.h[1]*inv + b[4*l+3];
    ushort4 o;
    o.x = f2bf(v0 > 0.f ? v0 : expm1f(v0));
    o.y = f2bf(v1 > 0.f ? v1 : expm1f(v1));
    o.z = f2bf(v2 > 0.f ? v2 : expm1f(v2));
    o.w = f2bf(v3 > 0.f ? v3 : expm1f(v3));
    *reinterpret_cast<ushort4*>(out + (size_t)n*D1 + 4*l) = o;
  }
}

// ---------------- Layer 2 fused: byte-offset csr, packed-f16, 4-edge unroll --
__global__ void l2_fused(const u16* __restrict__ xl, const u16* __restrict__ xr,
                         const int* __restrict__ off, const int* __restrict__ end,
                         const int* __restrict__ csr2,
                         const float* __restrict__ att,
                         const float* __restrict__ b, float* __restrict__ out){
  int tid = threadIdx.x;
  int lane = tid & 63;
  int g = (lane >> 4) & 1, l = lane & 15;
  int n = blockIdx.x*8 + (tid >> 6)*2 + (lane >> 5);
  if (n >= NN) return;
  int h = l >> 2;
  int c0 = 10*l;
  const char* xlb = (const char*)xl;
  int lo = 20*l;
  int wo = 320 + 2*h;
  hu xr2[5], a2[5];
  #pragma unroll
  for (int d = 0; d < 5; ++d){
    xr2[d].u = *reinterpret_cast<const unsigned*>(xr + (size_t)n*P2R + c0 + 2*d);
    a2[d].h[0] = (_Float16)(0.4f*L2E*att[c0 + 2*d]);
    a2[d].h[1] = (_Float16)(0.4f*L2E*att[c0 + 2*d + 1]);
  }
  float s = 0.f;
  hu acc2[5];
  #pragma unroll
  for (int d = 0; d < 5; ++d) acc2[d].u = 0;
  int p = off[n] + g, e1 = end[n];
  for (; p + 6 < e1; p += 8){
    unsigned bo[4];
    #pragma unroll
    for (int q = 0; q < 4; ++q) bo[q] = (unsigned)csr2[p + 2*q];
    hu xa[4][5]; u16 wv[4];
    #pragma unroll
    for (int q = 0; q < 4; ++q){
      const char* rp = xlb + bo[q] + lo;
      #pragma unroll
      for (int d = 0; d < 5; ++d) xa[q][d].u = *reinterpret_cast<const unsigned*>(rp + 4*d);
      wv[q] = *reinterpret_cast<const u16*>(xlb + bo[q] + wo);
    }
    #pragma unroll
    for (int q = 0; q < 4; ++q){
      hu t2; t2.u = 0;
      #pragma unroll
      for (int d = 0; d < 5; ++d){
        hu y; y.h = xa[q][d].h + xr2[d].h; y.u &= 0x7FFF7FFFu;
        t2.h = a2[d].h*y.h + t2.h;
      }
      float tf = (float)t2.h[0] + (float)t2.h[1];
      tf += __shfl_xor(tf, 1); tf += __shfl_xor(tf, 2);
      float pa = __builtin_amdgcn_exp2f(tf) * h16f(wv[q]);
      s += pa;
      hu pp; pp.h[0] = (_Float16)pa; pp.h[1] = pp.h[0];
      #pragma unroll
      for (int d = 0; d < 5; ++d) acc2[d].h = pp.h*xa[q][d].h + acc2[d].h;
    }
  }
  for (; p < e1; p += 2){
    unsigned bo = (unsigned)csr2[p];
    const char* rp = xlb + bo + lo;
    hu xa[5];
    #pragma unroll
    for (int d = 0; d < 5; ++d) xa[d].u = *reinterpret_cast<const unsigned*>(rp + 4*d);
    u16 wa16 = *reinterpret_cast<const u16*>(xlb + bo + wo);
    hu ta2; ta2.u = 0;
    #pragma unroll
    for (int d = 0; d < 5; ++d){
      hu ya; ya.h = xa[d].h + xr2[d].h; ya.u &= 0x7FFF7FFFu;
      ta2.h = a2[d].h*ya.h + ta2.h;
    }
    float ta = (float)ta2.h[0] + (float)ta2.h[1];
    ta += __shfl_xor(ta, 1); ta += __shfl_xor(ta, 2);
    float pa = __builtin_amdgcn_exp2f(ta) * h16f(wa16);
    s += pa;
    hu ppa; ppa.h[0] = (_Float16)pa; ppa.h[1] = ppa.h[0];
    #pragma unroll
    for (int d = 0; d < 5; ++d) acc2[d].h = ppa.h*xa[d].h + acc2[d].h;
  }
  s += __shfl_xor(s, 16);
  #pragma unroll
  for (int d = 0; d < 5; ++d){
    hu m; m.u = (unsigned)__shfl_xor((int)acc2[d].u, 16);
    acc2[d].h = acc2[d].h + m.h;
  }
  float inv = 1.f / (s + 1e-16f);
  float v[10];
  #pragma unroll
  for (int d = 0; d < 5; ++d){
    v[2*d]   = (float)acc2[d].h[0] * inv;
    v[2*d+1] = (float)acc2[d].h[1] * inv;
  }
  #pragma unroll
  for (int k = 0; k < 10; ++k){
    float o = v[k];
    o += __shfl_xor(o, 4);
    o += __shfl_xor(o, 8);
    v[k] = o*0.25f + b[10*(l & 3) + k];
  }
  float mx = v[0];
  #pragma unroll
  for (int k = 1; k < 10; ++k) mx = fmaxf(mx, v[k]);
  mx = fmaxf(mx, __shfl_xor(mx, 1));
  mx = fmaxf(mx, __shfl_xor(mx, 2));
  float es = 0.f;
  #pragma unroll
  for (int k = 0; k < 10; ++k) es += __expf(v[k] - mx);
  es += __shfl_xor(es, 1);
  es += __shfl_xor(es, 2);
  float lse = mx + __logf(es);
  if (g == 0 && l < 4){
    float* op = out + (size_t)n*C2 + 10*l;
    #pragma unroll
    for (int k2 = 0; k2 < 5; ++k2)
      *reinterpret_cast<float2*>(op + 2*k2) = make_float2(v[2*k2] - lse, v[2*k2+1] - lse);
  }
}

extern "C" void kernel_launch(void* const* d_in, const int* in_sizes, int n_in,
                              void* d_out, int out_size, void* d_ws, size_t ws_size,
                              hipStream_t stream){
  const float* x    = (const float*)d_in[0];
  const int*   ei   = (const int*)  d_in[1];
  const float* Wl1  = (const float*)d_in[2];
  const float* bl1  = (const float*)d_in[3];
  const float* Wr1  = (const float*)d_in[4];
  const float* br1  = (const float*)d_in[5];
  const float* att1 = (const float*)d_in[6];
  const float* b1   = (const float*)d_in[7];
  const float* Wl2  = (const float*)d_in[8];
  const float* bl2  = (const float*)d_in[9];
  const float* Wr2  = (const float*)d_in[10];
  const float* br2  = (const float*)d_in[11];
  const float* att2 = (const float*)d_in[12];
  const float* b2   = (const float*)d_in[13];
  float* out = (float*)d_out;

  char* ws = (char*)d_ws;
  u16*   B1     = (u16*)  (ws);                 // 14.4 MB: xl1 f16 [NN][72]
  u16*   B2     = (u16*)  (ws + 15000000);      // 14.4 MB: xr1 f16 [NN][72]
  u16*   h1     = (u16*)  (ws + 30000000);      // 12.8 MB: h1 bf16 [NN][64]
  u16*   B3     = (u16*)  (ws + 43000000);      // 33.6 MB: xl2 f16 [NN][168]
  u16*   B4     = (u16*)  (ws + 77000000);      // 33.6 MB: xr2 f16 [NN][168]
  int*   csrtmp = (int*)  (ws + 77000000);      // 7.82 MB, ALIASES B4
  int2*  ptmp   = (int2*) (ws + 86000000);      // 13.6 MB, ALIASES B4 (+9MB)
  float* WA1    = (float*)(ws + 111000000);     // 16 KB
  float* BA1    = (float*)(ws + 111100000);
  float* WA2    = (float*)(ws + 111200000);     // 2 KB
  float* BA2    = (float*)(ws + 111300000);
  int*   off    = (int*)  (ws + 111400000);     // 400 KB
  int*   end    = (int*)  (ws + 111900000);     // 400 KB
  int*   bcnt   = (int*)  (ws + 112400000);     // 1.6 KB
  int*   pcnt   = (int*)  (ws + 112450000);     // 100 B
  int*   csr1   = (int*)  (ws + 112500000);     // 7.82 MB
  int*   csr2   = (int*)  (ws + 120400000);     // 7.82 MB
  const int blk = 256;
  const int MB = (NN + 63)/64;                  // 1563 row-blocks

  // ---- CSR build (src-locality pre-sort -> dst partition -> per-bucket sort)
  hipMemsetAsync(bcnt, 0, (size_t)NBUCK*4, stream);
  hipMemsetAsync(pcnt, 0, (size_t)NSB*4, stream);
  psortA_k<<<(EE + 2047)/2048, blk, 0, stream>>>(ei, pcnt, ptmp);
  part1_k <<<NSB*BPB, blk, 0, stream>>>(ptmp, pcnt, bcnt, csrtmp);
  sort_k  <<<NBUCK, blk, 0, stream>>>(bcnt, csrtmp, csr1, csr2, off, end);
  wprep_k <<<19, blk, 0, stream>>>(Wl1, Wr1, att1, bl1, br1,
                                   Wl2, Wr2, att2, bl2, br2, WA1, BA1, WA2, BA2);

  // ---- layer 1 ----
  gemm1_mfma<<<MB, blk, 0, stream>>>(x, Wl1, bl1, Wr1, br1, WA1, BA1, B1, B2);
  l1_fused  <<<(NN + 7)/8, blk, 0, stream>>>(B1, B2, off, end, csr1, att1, b1, h1);

  // ---- layer 2 ----
  gemm2_mfma<<<MB, blk, 0, stream>>>(h1, Wl2, bl2, Wr2, br2, WA2, BA2, B3, B4);
  l2_fused  <<<(NN + 7)/8, blk, 0, stream>>>(B3, B4, off, end, csr2, att2, b2, out);
}

// Round 17
// 338.413 us; speedup vs baseline: 1.0965x; 1.0965x over previous
//
#include <hip/hip_runtime.h>
#include <math.h>

#define NN 100000
#define EE 1600000
#define FIN 256
#define D1 64
#define D2 160
#define C2 40
#define PK1 264   // gemm1 W LDS k-pitch
#define PK2 72    // gemm2 W LDS k-pitch
#define NBUCK 391 // ceil(NN/256) dst buckets
#define CAP 5000  // max edges per dst bucket incl. self loops
#define WSCL 0.015625f
#define L2E 1.442695041f

typedef unsigned short u16;
typedef __attribute__((ext_vector_type(8))) short bf16x8;
typedef __attribute__((ext_vector_type(4))) float f32x4;
typedef _Float16 h2t __attribute__((ext_vector_type(2)));
union hu { unsigned u; h2t h; };

__device__ __forceinline__ u16 f2bf(float f){
  unsigned b = __float_as_uint(f);
  return (u16)((b + 0x7FFFu + ((b >> 16) & 1u)) >> 16);   // RNE
}
__device__ __forceinline__ u16 f2h(float f){
  union { _Float16 h; u16 u; } c; c.h = (_Float16)f; return c.u;
}
__device__ __forceinline__ float h16f(u16 v){
  union { u16 u; _Float16 h; } c; c.u = v; return (float)c.h;
}

// ---------------- weight-side att precompute (parallel) ----------------
__global__ void wprep_k(const float* __restrict__ Wl1, const float* __restrict__ Wr1,
                        const float* __restrict__ att1,
                        const float* __restrict__ bl1, const float* __restrict__ br1,
                        const float* __restrict__ Wl2, const float* __restrict__ Wr2,
                        const float* __restrict__ att2,
                        const float* __restrict__ bl2, const float* __restrict__ br2,
                        float* __restrict__ WA1, float* __restrict__ BA1,
                        float* __restrict__ WA2, float* __restrict__ BA2){
  int t = blockIdx.x*256 + threadIdx.x;
  if (t < 4096){
    int k = t >> 4, j = t & 15;
    float v = 0.f;
    if (j < 8){
      float s = 0.f;
      #pragma unroll
      for (int c = 0; c < 8; ++c) s += Wl1[(size_t)k*D1 + j*8 + c] * att1[j*8 + c];
      v = 0.6f * s;
    }
    WA1[t] = v;
  } else if (t < 4608){
    int i = t - 4096;
    int k = i >> 3, j = i & 7;
    float v = 0.f;
    if (j < 4){
      float s = 0.f;
      #pragma unroll
      for (int c = 0; c < 40; ++c) s += Wl2[(size_t)k*D2 + j*40 + c] * att2[j*40 + c];
      v = 0.6f * s;
    }
    WA2[i] = v;
  } else if (t < 4616){
    int j = t - 4608;
    float s = 0.f;
    #pragma unroll
    for (int c = 0; c < 8; ++c) s += bl1[j*8 + c] * att1[j*8 + c];
    BA1[j] = 0.6f * s;
  } else if (t < 4620){
    int j = t - 4616;
    float s = 0.f;
    #pragma unroll
    for (int c = 0; c < 40; ++c) s += bl2[j*40 + c] * att2[j*40 + c];
    BA2[j] = 0.6f * s;
  }
}

// ---------------- CSR build: 2-pass bucketed counting sort ----------------
__global__ __launch_bounds__(256) void part1_k(const int* __restrict__ ei,
                                               int* __restrict__ bcnt,
                                               int* __restrict__ csrtmp){
  __shared__ int hist[NBUCK];
  __shared__ int gbase[NBUCK];
  int t = threadIdx.x;
  for (int i = t; i < NBUCK; i += 256) hist[i] = 0;
  __syncthreads();
  int rb[8], rr[8], rv[8];
  #pragma unroll
  for (int q = 0; q < 8; ++q){
    int e = blockIdx.x*2048 + q*256 + t;
    rb[q] = -1;
    if (e < EE){
      int s = ei[e], d = ei[EE + e];
      int b = d >> 8;
      rb[q] = b;
      rv[q] = s | ((d & 255) << 17);
      rr[q] = atomicAdd(&hist[b], 1);
    }
  }
  __syncthreads();
  for (int i = t; i < NBUCK; i += 256)
    if (hist[i] > 0) gbase[i] = atomicAdd(&bcnt[i], hist[i]);
  __syncthreads();
  #pragma unroll
  for (int q = 0; q < 8; ++q){
    if (rb[q] >= 0){
      int pos = gbase[rb[q]] + rr[q];
      if (pos < CAP) csrtmp[rb[q]*CAP + pos] = rv[q];
    }
  }
}

// pass 2: per-bucket LDS counting sort; self loop seeded first.
// csr1 = src*128 (l1 row byte offset); csr2 = src*8 (l2 omega byte offset;
// row byte offset = csr2*40).
__global__ __launch_bounds__(256) void sort_k(const int* __restrict__ bcnt,
                                              const int* __restrict__ csrtmp,
                                              int* __restrict__ csr1,
                                              int* __restrict__ csr2,
                                              int* __restrict__ off,
                                              int* __restrict__ end){
  __shared__ int cnt[256];
  __shared__ int sc[256];
  __shared__ int cur[256];
  int b = blockIdx.x, t = threadIdx.x;
  int E = bcnt[b]; if (E > CAP) E = CAP;
  int n = (b << 8) + t;
  cnt[t] = (n < NN) ? 1 : 0;          // self edge
  __syncthreads();
  for (int i = t; i < E; i += 256){
    int v = csrtmp[b*CAP + i];
    atomicAdd(&cnt[(v >> 17) & 255], 1);
  }
  __syncthreads();
  int x = cnt[t];
  sc[t] = x;
  __syncthreads();
  for (int o = 1; o < 256; o <<= 1){
    int v = (t >= o) ? sc[t - o] : 0;
    __syncthreads();
    sc[t] += v;
    __syncthreads();
  }
  int excl = sc[t] - x;
  if (n < NN){
    off[n] = b*CAP + excl;
    end[n] = b*CAP + excl + x;
    csr1[b*CAP + excl] = n * 128;     // self edge first
    csr2[b*CAP + excl] = n * 8;
    cur[t] = excl + 1;
  } else {
    cur[t] = excl;
  }
  __syncthreads();
  for (int i = t; i < E; i += 256){
    int v = csrtmp[b*CAP + i];
    int p = atomicAdd(&cur[(v >> 17) & 255], 1);
    int src = v & 0x1FFFF;
    csr1[b*CAP + p] = src * 128;
    csr2[b*CAP + p] = src * 8;
  }
}

// ---------------- layer-1 MFMA GEMM; rows 64ch f16 + separate omega ----------
__global__ __launch_bounds__(256) void gemm1_mfma(
    const float* __restrict__ X,
    const float* __restrict__ Wl, const float* __restrict__ bl,
    const float* __restrict__ Wr, const float* __restrict__ br,
    const float* __restrict__ WA1, const float* __restrict__ BA1,
    u16* __restrict__ outl, u16* __restrict__ outr, u16* __restrict__ w1){
  __shared__ u16 WB[144*PK1];   // 76 KB
  int t = threadIdx.x;
  #pragma unroll
  for (int q = 0; q < 16; ++q){
    int idx = t + 256*q;
    int k = idx >> 4, c4 = idx & 15;
    float4 vl = *reinterpret_cast<const float4*>(Wl + (size_t)k*D1 + c4*4);
    float4 vr = *reinterpret_cast<const float4*>(Wr + (size_t)k*D1 + c4*4);
    WB[(c4*4+0)*PK1 + k] = f2bf(vl.x); WB[(c4*4+1)*PK1 + k] = f2bf(vl.y);
    WB[(c4*4+2)*PK1 + k] = f2bf(vl.z); WB[(c4*4+3)*PK1 + k] = f2bf(vl.w);
    WB[(64+c4*4+0)*PK1 + k] = f2bf(vr.x); WB[(64+c4*4+1)*PK1 + k] = f2bf(vr.y);
    WB[(64+c4*4+2)*PK1 + k] = f2bf(vr.z); WB[(64+c4*4+3)*PK1 + k] = f2bf(vr.w);
  }
  #pragma unroll
  for (int q = 0; q < 16; ++q){
    int idx = t + 256*q;
    int k = idx >> 4, j = idx & 15;
    WB[(128+j)*PK1 + k] = f2bf(WA1[k*16 + j]);
  }
  __syncthreads();
  int w = t >> 6, l = t & 63;
  int g = l >> 4;
  int arow = blockIdx.x*64 + w*16 + (l & 15);
  if (arow >= NN) arow = NN-1;
  const float* xp = X + (size_t)arow*FIN + g*8;
  f32x4 acc[9] = {};
  #pragma unroll
  for (int kk = 0; kk < 8; ++kk){
    float4 a0 = *reinterpret_cast<const float4*>(xp + kk*32);
    float4 a1 = *reinterpret_cast<const float4*>(xp + kk*32 + 4);
    union { bf16x8 v; u16 u[8]; } A;
    A.u[0]=f2bf(a0.x); A.u[1]=f2bf(a0.y); A.u[2]=f2bf(a0.z); A.u[3]=f2bf(a0.w);
    A.u[4]=f2bf(a1.x); A.u[5]=f2bf(a1.y); A.u[6]=f2bf(a1.z); A.u[7]=f2bf(a1.w);
    const u16* wb = WB + (l & 15)*PK1 + kk*32 + g*8;
    #pragma unroll
    for (int c = 0; c < 9; ++c){
      bf16x8 B = *reinterpret_cast<const bf16x8*>(wb + c*16*PK1);
      acc[c] = __builtin_amdgcn_mfma_f32_16x16x32_bf16(A.v, B, acc[c], 0, 0, 0);
    }
  }
  int ocol = l & 15;
  int orow0 = blockIdx.x*64 + w*16 + g*4;
  #pragma unroll
  for (int c = 0; c < 8; ++c){
    bool left = (c < 4);
    int col = (left ? c : c-4)*16 + ocol;
    u16* op = left ? outl : outr;
    float bv = (left ? bl : br)[col];
    #pragma unroll
    for (int r = 0; r < 4; ++r){
      int row = orow0 + r;
      if (row < NN) op[(size_t)row*D1 + col] = f2h(acc[c][r] + bv);
    }
  }
  if (ocol < 8){
    float bav = BA1[ocol];
    #pragma unroll
    for (int r = 0; r < 4; ++r){
      int row = orow0 + r;
      if (row < NN) w1[(size_t)row*8 + ocol] = f2h(__expf(acc[8][r] + bav) * WSCL);
    }
  }
}

// ---------------- layer-2 dual MFMA GEMM; rows 160ch f16 + separate omega ----
__global__ __launch_bounds__(256) void gemm2_mfma(
    const u16* __restrict__ H,
    const float* __restrict__ Wl, const float* __restrict__ bl,
    const float* __restrict__ Wr, const float* __restrict__ br,
    const float* __restrict__ WA2, const float* __restrict__ BA2,
    u16* __restrict__ outl, u16* __restrict__ outr, u16* __restrict__ w2){
  __shared__ u16 WB[336*PK2];   // 48.4 KB
  int t = threadIdx.x;
  #pragma unroll
  for (int q = 0; q < 10; ++q){
    int idx = t + 256*q;
    int k = idx / 40, c4 = idx % 40;
    float4 vl = *reinterpret_cast<const float4*>(Wl + (size_t)k*D2 + c4*4);
    float4 vr = *reinterpret_cast<const float4*>(Wr + (size_t)k*D2 + c4*4);
    WB[(c4*4+0)*PK2 + k] = f2bf(vl.x); WB[(c4*4+1)*PK2 + k] = f2bf(vl.y);
    WB[(c4*4+2)*PK2 + k] = f2bf(vl.z); WB[(c4*4+3)*PK2 + k] = f2bf(vl.w);
    WB[(160+c4*4+0)*PK2 + k] = f2bf(vr.x); WB[(160+c4*4+1)*PK2 + k] = f2bf(vr.y);
    WB[(160+c4*4+2)*PK2 + k] = f2bf(vr.z); WB[(160+c4*4+3)*PK2 + k] = f2bf(vr.w);
  }
  #pragma unroll
  for (int q = 0; q < 2; ++q){
    int i2 = t + 256*q;
    int k = i2 >> 3, j = i2 & 7;
    WB[(320+j)*PK2 + k] = f2bf(WA2[k*8 + j]);
    WB[(328+j)*PK2 + k] = 0;
  }
  __syncthreads();
  int w = t >> 6, l = t & 63;
  int g = l >> 4;
  int arow = blockIdx.x*64 + w*16 + (l & 15);
  if (arow >= NN) arow = NN-1;
  const u16* hp = H + (size_t)arow*D1 + g*8;
  f32x4 acc[21] = {};
  #pragma unroll
  for (int kk = 0; kk < 2; ++kk){
    bf16x8 A = *reinterpret_cast<const bf16x8*>(hp + kk*32);
    const u16* wb = WB + (l & 15)*PK2 + kk*32 + g*8;
    #pragma unroll
    for (int c = 0; c < 21; ++c){
      bf16x8 B = *reinterpret_cast<const bf16x8*>(wb + c*16*PK2);
      acc[c] = __builtin_amdgcn_mfma_f32_16x16x32_bf16(A, B, acc[c], 0, 0, 0);
    }
  }
  int ocol = l & 15;
  int orow0 = blockIdx.x*64 + w*16 + g*4;
  #pragma unroll
  for (int c = 0; c < 20; ++c){
    bool left = (c < 10);
    int col = (left ? c : c-10)*16 + ocol;
    u16* op = left ? outl : outr;
    float bv = (left ? bl : br)[col];
    #pragma unroll
    for (int r = 0; r < 4; ++r){
      int row = orow0 + r;
      if (row < NN) op[(size_t)row*D2 + col] = f2h(acc[c][r] + bv);
    }
  }
  if (ocol < 4){
    float bav = BA2[ocol];
    #pragma unroll
    for (int r = 0; r < 4; ++r){
      int row = orow0 + r;
      if (row < NN) w2[(size_t)row*4 + ocol] = f2h(__expf(acc[20][r] + bav) * WSCL);
    }
  }
}

// ---------------- Layer 1 fused: 128-B rows, separate omega ----------------
__global__ void l1_fused(const u16* __restrict__ xl, const u16* __restrict__ xr,
                         const u16* __restrict__ w1,
                         const int* __restrict__ off, const int* __restrict__ end,
                         const int* __restrict__ csr1,
                         const float* __restrict__ att,
                         const float* __restrict__ b, u16* __restrict__ out){
  int tid = threadIdx.x;
  int lane = tid & 63;
  int g = (lane >> 4) & 1, l = lane & 15;
  int n = blockIdx.x*8 + (tid >> 6)*2 + (lane >> 5);
  if (n >= NN) return;
  int h = l >> 1;
  const char* xlb = (const char*)xl;
  const char* w1b = (const char*)w1;
  int lo = 8*l;
  int wo = 2*h;
  uint2 xru = *reinterpret_cast<const uint2*>(xr + (size_t)n*D1 + 4*l);
  hu r0, r1; r0.u = xru.x; r1.u = xru.y;
  hu a0, a1;
  a0.h[0] = (_Float16)(0.4f*L2E*att[4*l+0]); a0.h[1] = (_Float16)(0.4f*L2E*att[4*l+1]);
  a1.h[0] = (_Float16)(0.4f*L2E*att[4*l+2]); a1.h[1] = (_Float16)(0.4f*L2E*att[4*l+3]);
  float s = 0.f;
  hu acc0, acc1; acc0.u = 0; acc1.u = 0;
  int p = off[n] + g, e1 = end[n];
  for (; p + 6 < e1; p += 8){
    unsigned bo[4];
    #pragma unroll
    for (int q = 0; q < 4; ++q) bo[q] = (unsigned)csr1[p + 2*q];
    uint2 uv[4]; u16 wv[4];
    #pragma unroll
    for (int q = 0; q < 4; ++q){
      uv[q] = *reinterpret_cast<const uint2*>(xlb + bo[q] + lo);
      wv[q] = *reinterpret_cast<const u16*>(w1b + (bo[q] >> 3) + wo);
    }
    #pragma unroll
    for (int q = 0; q < 4; ++q){
      hu x0, x1; x0.u = uv[q].x; x1.u = uv[q].y;
      hu y0, y1; y0.h = x0.h + r0.h; y1.h = x1.h + r1.h;
      y0.u &= 0x7FFF7FFFu; y1.u &= 0x7FFF7FFFu;
      hu t2; t2.h = a0.h*y0.h + a1.h*y1.h;
      float tf = (float)t2.h[0] + (float)t2.h[1];
      tf += __shfl_xor(tf, 1);
      float pa = __builtin_amdgcn_exp2f(tf) * h16f(wv[q]);
      s += pa;
      hu pp; pp.h[0] = (_Float16)pa; pp.h[1] = pp.h[0];
      acc0.h = pp.h*x0.h + acc0.h;
      acc1.h = pp.h*x1.h + acc1.h;
    }
  }
  for (; p < e1; p += 2){
    unsigned bo = (unsigned)csr1[p];
    uint2 ua = *reinterpret_cast<const uint2*>(xlb + bo + lo);
    u16 wa = *reinterpret_cast<const u16*>(w1b + (bo >> 3) + wo);
    hu x0, x1; x0.u = ua.x; x1.u = ua.y;
    hu y0, y1; y0.h = x0.h + r0.h; y1.h = x1.h + r1.h;
    y0.u &= 0x7FFF7FFFu; y1.u &= 0x7FFF7FFFu;
    hu t2; t2.h = a0.h*y0.h + a1.h*y1.h;
    float tf = (float)t2.h[0] + (float)t2.h[1];
    tf += __shfl_xor(tf, 1);
    float pa = __builtin_amdgcn_exp2f(tf) * h16f(wa);
    s += pa;
    hu pp; pp.h[0] = (_Float16)pa; pp.h[1] = pp.h[0];
    acc0.h = pp.h*x0.h + acc0.h;
    acc1.h = pp.h*x1.h + acc1.h;
  }
  s += __shfl_xor(s, 16);
  { hu m; m.u = (unsigned)__shfl_xor((int)acc0.u, 16); acc0.h = acc0.h + m.h; }
  { hu m; m.u = (unsigned)__shfl_xor((int)acc1.u, 16); acc1.h = acc1.h + m.h; }
  if (g == 0){
    float inv = 1.f / (s + 1e-16f);
    float v0 = (float)acc0.h[0]*inv + b[4*l+0];
    float v1 = (float)acc0.h[1]*inv + b[4*l+1];
    float v2 = (float)acc1.h[0]*inv + b[4*l+2];
    float v3 = (float)acc1.h[1]*inv + b[4*l+3];
    ushort4 o;
    o.x = f2bf(v0 > 0.f ? v0 : expm1f(v0));
    o.y = f2bf(v1 > 0.f ? v1 : expm1f(v1));
    o.z = f2bf(v2 > 0.f ? v2 : expm1f(v2));
    o.w = f2bf(v3 > 0.f ? v3 : expm1f(v3));
    *reinterpret_cast<ushort4*>(out + (size_t)n*D1 + 4*l) = o;
  }
}

// ---------------- Layer 2 fused: 320-B rows, separate omega ----------------
// csr2 holds src*8; row byte offset = csr2*40 (inline-const mul).
__global__ void l2_fused(const u16* __restrict__ xl, const u16* __restrict__ xr,
                         const u16* __restrict__ w2,
                         const int* __restrict__ off, const int* __restrict__ end,
                         const int* __restrict__ csr2,
                         const float* __restrict__ att,
                         const float* __restrict__ b, float* __restrict__ out){
  int tid = threadIdx.x;
  int lane = tid & 63;
  int g = (lane >> 4) & 1, l = lane & 15;
  int n = blockIdx.x*8 + (tid >> 6)*2 + (lane >> 5);
  if (n >= NN) return;
  int h = l >> 2;
  int c0 = 10*l;
  const char* xlb = (const char*)xl;
  const char* w2b = (const char*)w2;
  int lo = 20*l;
  int wo = 2*h;
  hu xr2[5], a2[5];
  #pragma unroll
  for (int d = 0; d < 5; ++d){
    xr2[d].u = *reinterpret_cast<const unsigned*>(xr + (size_t)n*D2 + c0 + 2*d);
    a2[d].h[0] = (_Float16)(0.4f*L2E*att[c0 + 2*d]);
    a2[d].h[1] = (_Float16)(0.4f*L2E*att[c0 + 2*d + 1]);
  }
  float s = 0.f;
  hu acc2[5];
  #pragma unroll
  for (int d = 0; d < 5; ++d) acc2[d].u = 0;
  int p = off[n] + g, e1 = end[n];
  for (; p + 6 < e1; p += 8){
    unsigned b8[4];
    #pragma unroll
    for (int q = 0; q < 4; ++q) b8[q] = (unsigned)csr2[p + 2*q];
    hu xa[4][5]; u16 wv[4];
    #pragma unroll
    for (int q = 0; q < 4; ++q){
      const char* rp = xlb + b8[q]*40u + lo;
      #pragma unroll
      for (int d = 0; d < 5; ++d) xa[q][d].u = *reinterpret_cast<const unsigned*>(rp + 4*d);
      wv[q] = *reinterpret_cast<const u16*>(w2b + b8[q] + wo);
    }
    #pragma unroll
    for (int q = 0; q < 4; ++q){
      hu t2; t2.u = 0;
      #pragma unroll
      for (int d = 0; d < 5; ++d){
        hu y; y.h = xa[q][d].h + xr2[d].h; y.u &= 0x7FFF7FFFu;
        t2.h = a2[d].h*y.h + t2.h;
      }
      float tf = (float)t2.h[0] + (float)t2.h[1];
      tf += __shfl_xor(tf, 1); tf += __shfl_xor(tf, 2);
      float pa = __builtin_amdgcn_exp2f(tf) * h16f(wv[q]);
      s += pa;
      hu pp; pp.h[0] = (_Float16)pa; pp.h[1] = pp.h[0];
      #pragma unroll
      for (int d = 0; d < 5; ++d) acc2[d].h = pp.h*xa[q][d].h + acc2[d].h;
    }
  }
  for (; p < e1; p += 2){
    unsigned b8 = (unsigned)csr2[p];
    const char* rp = xlb + b8*40u + lo;
    hu xa[5];
    #pragma unroll
    for (int d = 0; d < 5; ++d) xa[d].u = *reinterpret_cast<const unsigned*>(rp + 4*d);
    u16 wa16 = *reinterpret_cast<const u16*>(w2b + b8 + wo);
    hu ta2; ta2.u = 0;
    #pragma unroll
    for (int d = 0; d < 5; ++d){
      hu ya; ya.h = xa[d].h + xr2[d].h; ya.u &= 0x7FFF7FFFu;
      ta2.h = a2[d].h*ya.h + ta2.h;
    }
    float ta = (float)ta2.h[0] + (float)ta2.h[1];
    ta += __shfl_xor(ta, 1); ta += __shfl_xor(ta, 2);
    float pa = __builtin_amdgcn_exp2f(ta) * h16f(wa16);
    s += pa;
    hu ppa; ppa.h[0] = (_Float16)pa; ppa.h[1] = ppa.h[0];
    #pragma unroll
    for (int d = 0; d < 5; ++d) acc2[d].h = ppa.h*xa[d].h + acc2[d].h;
  }
  s += __shfl_xor(s, 16);
  #pragma unroll
  for (int d = 0; d < 5; ++d){
    hu m; m.u = (unsigned)__shfl_xor((int)acc2[d].u, 16);
    acc2[d].h = acc2[d].h + m.h;
  }
  float inv = 1.f / (s + 1e-16f);
  float v[10];
  #pragma unroll
  for (int d = 0; d < 5; ++d){
    v[2*d]   = (float)acc2[d].h[0] * inv;
    v[2*d+1] = (float)acc2[d].h[1] * inv;
  }
  #pragma unroll
  for (int k = 0; k < 10; ++k){
    float o = v[k];
    o += __shfl_xor(o, 4);
    o += __shfl_xor(o, 8);
    v[k] = o*0.25f + b[10*(l & 3) + k];
  }
  float mx = v[0];
  #pragma unroll
  for (int k = 1; k < 10; ++k) mx = fmaxf(mx, v[k]);
  mx = fmaxf(mx, __shfl_xor(mx, 1));
  mx = fmaxf(mx, __shfl_xor(mx, 2));
  float es = 0.f;
  #pragma unroll
  for (int k = 0; k < 10; ++k) es += __expf(v[k] - mx);
  es += __shfl_xor(es, 1);
  es += __shfl_xor(es, 2);
  float lse = mx + __logf(es);
  if (g == 0 && l < 4){
    float* op = out + (size_t)n*C2 + 10*l;
    #pragma unroll
    for (int k2 = 0; k2 < 5; ++k2)
      *reinterpret_cast<float2*>(op + 2*k2) = make_float2(v[2*k2] - lse, v[2*k2+1] - lse);
  }
}

extern "C" void kernel_launch(void* const* d_in, const int* in_sizes, int n_in,
                              void* d_out, int out_size, void* d_ws, size_t ws_size,
                              hipStream_t stream){
  const float* x    = (const float*)d_in[0];
  const int*   ei   = (const int*)  d_in[1];
  const float* Wl1  = (const float*)d_in[2];
  const float* bl1  = (const float*)d_in[3];
  const float* Wr1  = (const float*)d_in[4];
  const float* br1  = (const float*)d_in[5];
  const float* att1 = (const float*)d_in[6];
  const float* b1   = (const float*)d_in[7];
  const float* Wl2  = (const float*)d_in[8];
  const float* bl2  = (const float*)d_in[9];
  const float* Wr2  = (const float*)d_in[10];
  const float* br2  = (const float*)d_in[11];
  const float* att2 = (const float*)d_in[12];
  const float* b2   = (const float*)d_in[13];
  float* out = (float*)d_out;

  char* ws = (char*)d_ws;
  u16*   B1     = (u16*)  (ws);                 // 12.8 MB: xl1 f16 [NN][64]
  u16*   B2     = (u16*)  (ws + 13000000);      // 12.8 MB: xr1 f16 [NN][64]
  u16*   W1     = (u16*)  (ws + 26000000);      // 1.6 MB: omega1 [NN][8]
  u16*   h1     = (u16*)  (ws + 28000000);      // 12.8 MB: h1 bf16 [NN][64]
  u16*   B3     = (u16*)  (ws + 41000000);      // 32 MB: xl2 f16 [NN][160]
  u16*   W2     = (u16*)  (ws + 73500000);      // 0.8 MB: omega2 [NN][4]
  u16*   B4     = (u16*)  (ws + 74500000);      // 32 MB: xr2 f16 [NN][160]
  int*   csrtmp = (int*)  (ws + 74500000);      // 7.82 MB, ALIASES B4 (dead before gemm2)
  float* WA1    = (float*)(ws + 107000000);     // 16 KB
  float* BA1    = (float*)(ws + 107100000);
  float* WA2    = (float*)(ws + 107200000);     // 2 KB
  float* BA2    = (float*)(ws + 107300000);
  int*   off    = (int*)  (ws + 107400000);     // 400 KB
  int*   end    = (int*)  (ws + 107900000);     // 400 KB
  int*   bcnt   = (int*)  (ws + 108400000);     // 1.6 KB
  int*   csr1   = (int*)  (ws + 108500000);     // 7.82 MB: src*128
  int*   csr2   = (int*)  (ws + 116400000);     // 7.82 MB: src*8
  const int blk = 256;
  const int MB = (NN + 63)/64;                  // 1563 row-blocks

  // ---- CSR build + weight precompute ----
  hipMemsetAsync(bcnt, 0, (size_t)NBUCK*4, stream);
  part1_k<<<(EE + 2047)/2048, blk, 0, stream>>>(ei, bcnt, csrtmp);
  sort_k <<<NBUCK, blk, 0, stream>>>(bcnt, csrtmp, csr1, csr2, off, end);
  wprep_k<<<19, blk, 0, stream>>>(Wl1, Wr1, att1, bl1, br1,
                                  Wl2, Wr2, att2, bl2, br2, WA1, BA1, WA2, BA2);

  // ---- layer 1 ----
  gemm1_mfma<<<MB, blk, 0, stream>>>(x, Wl1, bl1, Wr1, br1, WA1, BA1, B1, B2, W1);
  l1_fused  <<<(NN + 7)/8, blk, 0, stream>>>(B1, B2, W1, off, end, csr1, att1, b1, h1);

  // ---- layer 2 ----
  gemm2_mfma<<<MB, blk, 0, stream>>>(h1, Wl2, bl2, Wr2, br2, WA2, BA2, B3, B4, W2);
  l2_fused  <<<(NN + 7)/8, blk, 0, stream>>>(B3, B4, W2, off, end, csr2, att2, b2, out);
}